// Round 5
// baseline (149.678 us; speedup 1.0000x reference)
//
#include <hip/hip_runtime.h>

#define NSEG 17

// ---------------- ws layout ----------------
// [0,    272)          : float sums[4][17]
// [272,  544)          : int   counts[4][17]
// [1024, 1024+131072)  : uint8 seg0[8*128*128]   (scale-0 segment map)

__global__ void init_accum(float* __restrict__ sums, int* __restrict__ counts) {
    int t = threadIdx.x;
    if (t < 4 * NSEG) { sums[t] = 0.0f; counts[t] = 0; }
}

// One thread per scale-0 pixel: seg map + per-scale counts.
__global__ __launch_bounds__(256) void seg_count_kernel(
    const int* __restrict__ labels,         // [8,512,512]
    const float* __restrict__ outputs_old,  // [8,OC,512,512]
    unsigned char* __restrict__ seg0,       // [8,128,128]
    int* __restrict__ counts,               // [4][17]
    int OC)
{
    __shared__ int cbins[4 * NSEG];
    int t = threadIdx.x;
    if (t < 4 * NSEG) cbins[t] = 0;
    __syncthreads();

    int p = blockIdx.x * 256 + t;           // [0, 131072)
    int b = p >> 14;
    int y = (p >> 7) & 127;
    int x = p & 127;
    int y0 = y << 2, x0 = x << 2;           // sampled position in 512 grid

    int lbl = labels[(b << 18) + (y0 << 9) + x0];

    // thresholded argmax over channels, first-index-of-max (jnp.argmax semantics)
    const float* base = outputs_old + (((size_t)b * OC) << 18) + (y0 << 9) + x0;
    float v0 = base[0];
    float best = (v0 < 0.5f) ? 0.0f : v0;
    int bidx = 0;
    for (int c = 1; c < OC; ++c) {
        float v = base[(size_t)c << 18];
        v = (v < 0.5f) ? 0.0f : v;
        if (v > best) { best = v; bidx = c; }   // strict > keeps first index
    }

    int nold = OC - 1;
    int pl = (lbl == 0) ? bidx : lbl;
    int seg = (pl <= nold) ? pl : (nold + 1);
    seg0[p] = (unsigned char)seg;

    atomicAdd(&cbins[seg], 1);
    if (((y | x) & 1) == 0) atomicAdd(&cbins[NSEG + seg], 1);
    if (((y | x) & 3) == 0) atomicAdd(&cbins[2 * NSEG + seg], 1);
    if (((y | x) & 7) == 0) atomicAdd(&cbins[3 * NSEG + seg], 1);
    __syncthreads();
    if (t < 4 * NSEG) {
        int c = cbins[t];
        if (c) atomicAdd(&counts[t], c);
    }
}

// Fused per-scale channel-sum of squared diffs, segment-binned.
// Blocks: [0,1024) s0, [1024,2048) s1, [2048,3072) s2, [3072,3584) s3.
__global__ __launch_bounds__(256) void sq_sum_kernel(
    const float* __restrict__ f0, const float* __restrict__ o0,
    const float* __restrict__ f1, const float* __restrict__ o1,
    const float* __restrict__ f2, const float* __restrict__ o2,
    const float* __restrict__ f3, const float* __restrict__ o3,
    const unsigned char* __restrict__ seg0,
    float* __restrict__ sums)
{
    __shared__ float bins[NSEG];
    if (threadIdx.x < NSEG) bins[threadIdx.x] = 0.0f;
    __syncthreads();

    int blk = blockIdx.x;
    int s, bstart, C, lq, CH, lqpi, lw4, fsL;
    const float *F, *O;
    if (blk < 1024)      { s=0; bstart=0;    C=256;  lq=15; CH=32; lqpi=12; lw4=5; fsL=0; F=f0; O=o0; }
    else if (blk < 2048) { s=1; bstart=1024; C=512;  lq=13; CH=16; lqpi=10; lw4=4; fsL=1; F=f1; O=o1; }
    else if (blk < 3072) { s=2; bstart=2048; C=1024; lq=11; CH=8;  lqpi=8;  lw4=3; fsL=2; F=f2; O=o2; }
    else                 { s=3; bstart=3072; C=2048; lq=9;  CH=8;  lqpi=6;  lw4=2; fsL=3; F=f3; O=o3; }

    int hw4 = 1 << lqpi;                      // float4s per (b,c) plane = h*w/4
    int tid = (blk - bstart) * 256 + threadIdx.x;
    int qid = tid & ((1 << lq) - 1);          // pixel-quad id
    int c0  = (tid >> lq) * CH;               // first channel of this thread's chunk

    int b = qid >> lqpi;
    int within = qid & (hw4 - 1);             // quad index inside the plane

    size_t base4 = (size_t)(b * C + c0) * hw4 + within;
    const float4* pF = reinterpret_cast<const float4*>(F) + base4;
    const float4* pO = reinterpret_cast<const float4*>(O) + base4;

    float a0 = 0.f, a1 = 0.f, a2 = 0.f, a3 = 0.f;
    for (int i = 0; i < CH; ++i) {
        float4 a = pF[(size_t)i * hw4];
        float4 o = pO[(size_t)i * hw4];
        float d0 = a.x - o.x, d1 = a.y - o.y, d2 = a.z - o.z, d3 = a.w - o.w;
        a0 = fmaf(d0, d0, a0); a1 = fmaf(d1, d1, a1);
        a2 = fmaf(d2, d2, a2); a3 = fmaf(d3, d3, a3);
    }

    // segment of each of the 4 pixels (map to scale-0 grid: *2^fsL)
    int y  = within >> lw4;
    int xq = within & ((1 << lw4) - 1);
    int segBase = (b << 14) + ((y << fsL) << 7) + ((xq << 2) << fsL);
    atomicAdd(&bins[seg0[segBase]], a0);
    atomicAdd(&bins[seg0[segBase + (1 << fsL)]], a1);
    atomicAdd(&bins[seg0[segBase + (2 << fsL)]], a2);
    atomicAdd(&bins[seg0[segBase + (3 << fsL)]], a3);

    __syncthreads();
    if (threadIdx.x < NSEG) {
        float v = bins[threadIdx.x];
        if (v != 0.0f) atomicAdd(&sums[s * NSEG + threadIdx.x], v);
    }
}

__global__ void finalize_kernel(const float* __restrict__ sums,
                                const int* __restrict__ counts,
                                const int* __restrict__ p_ncls,
                                const int* __restrict__ p_nold,
                                int OC,
                                float* __restrict__ out)
{
    if (threadIdx.x != 0 || blockIdx.x != 0) return;
    int nold = p_nold[0];
    if (nold < 1 || nold > 100) nold = OC - 1;       // sanity fallback
    int ncls = p_ncls[0];
    if (ncls <= nold || ncls > 1000) ncls = 21;      // sanity fallback
    float w0 = (float)nold / (float)ncls;

    float loss = 0.0f;
    for (int s = 0; s < 4; ++s) {
        float Cs = (float)(256 << s);
        float sw = (float)(s + 1);                   // SCALE_WEIGHTS 1,2,3,4
        float acc = 0.0f;
        for (int g = 0; g <= nold; ++g) {            // dump bucket (g=nold+1) weight 0
            float w = (g == 0) ? w0 : 1.0f;
            int cnt = counts[s * NSEG + g];
            if (cnt > 0) acc += w * sums[s * NSEG + g] / ((float)cnt * Cs);
        }
        loss += sw * acc;
    }
    out[0] = loss * 0.25f;
}

extern "C" void kernel_launch(void* const* d_in, const int* in_sizes, int n_in,
                              void* d_out, int out_size, void* d_ws, size_t ws_size,
                              hipStream_t stream) {
    // setup_inputs dict order:
    // labels, outputs_old, feat0, feat_old0, feat1, feat_old1,
    // feat2, feat_old2, feat3, feat_old3, num_class, num_old_class
    const int*   labels      = (const int*)d_in[0];
    const float* outputs_old = (const float*)d_in[1];
    const float* f0 = (const float*)d_in[2];
    const float* o0 = (const float*)d_in[3];
    const float* f1 = (const float*)d_in[4];
    const float* o1 = (const float*)d_in[5];
    const float* f2 = (const float*)d_in[6];
    const float* o2 = (const float*)d_in[7];
    const float* f3 = (const float*)d_in[8];
    const float* o3 = (const float*)d_in[9];
    const int* p_ncls = (const int*)d_in[10];
    const int* p_nold = (const int*)d_in[11];

    int OC = in_sizes[1] / in_sizes[0];   // outputs_old channels = num_old_class + 1 = 16

    float* sums  = (float*)d_ws;
    int*   counts = (int*)((char*)d_ws + 4 * NSEG * sizeof(float));
    unsigned char* seg0 = (unsigned char*)d_ws + 1024;

    hipLaunchKernelGGL(init_accum, dim3(1), dim3(256), 0, stream, sums, counts);
    hipLaunchKernelGGL(seg_count_kernel, dim3(512), dim3(256), 0, stream,
                       labels, outputs_old, seg0, counts, OC);
    hipLaunchKernelGGL(sq_sum_kernel, dim3(3584), dim3(256), 0, stream,
                       f0, o0, f1, o1, f2, o2, f3, o3, seg0, sums);
    hipLaunchKernelGGL(finalize_kernel, dim3(1), dim3(64), 0, stream,
                       sums, counts, p_ncls, p_nold, OC, (float*)d_out);
}

// Round 6
// 138.375 us; speedup vs baseline: 1.0817x; 1.0817x over previous
//
#include <hip/hip_runtime.h>

#define NSEG 17

// ---------------- ws layout ----------------
// [0,    272)          : float sums[4][17]
// [272,  544)          : int   counts[4][17]
// [1024, 1024+131072)  : uint8 seg0[8*128*128]   (scale-0 segment map)

__global__ void init_accum(float* __restrict__ sums, int* __restrict__ counts) {
    int t = threadIdx.x;
    if (t < 4 * NSEG) { sums[t] = 0.0f; counts[t] = 0; }
}

// One thread per scale-0 pixel: seg map + per-scale counts.
__global__ __launch_bounds__(256) void seg_count_kernel(
    const int* __restrict__ labels,         // [8,512,512]
    const float* __restrict__ outputs_old,  // [8,OC,512,512]
    unsigned char* __restrict__ seg0,       // [8,128,128]
    int* __restrict__ counts,               // [4][17]
    int OC)
{
    __shared__ int cbins[4 * NSEG];
    int t = threadIdx.x;
    if (t < 4 * NSEG) cbins[t] = 0;
    __syncthreads();

    int p = blockIdx.x * 256 + t;           // [0, 131072)
    int b = p >> 14;
    int y = (p >> 7) & 127;
    int x = p & 127;
    int y0 = y << 2, x0 = x << 2;           // sampled position in 512 grid

    int lbl = labels[(b << 18) + (y0 << 9) + x0];

    // thresholded argmax over channels, first-index-of-max (jnp.argmax semantics)
    const float* base = outputs_old + (((size_t)b * OC) << 18) + (y0 << 9) + x0;
    float v0 = base[0];
    float best = (v0 < 0.5f) ? 0.0f : v0;
    int bidx = 0;
    #pragma unroll 4
    for (int c = 1; c < OC; ++c) {
        float v = base[(size_t)c << 18];
        v = (v < 0.5f) ? 0.0f : v;
        if (v > best) { best = v; bidx = c; }   // strict > keeps first index
    }

    int nold = OC - 1;
    int pl = (lbl == 0) ? bidx : lbl;
    int seg = (pl <= nold) ? pl : (nold + 1);
    seg0[p] = (unsigned char)seg;

    atomicAdd(&cbins[seg], 1);
    if (((y | x) & 1) == 0) atomicAdd(&cbins[NSEG + seg], 1);
    if (((y | x) & 3) == 0) atomicAdd(&cbins[2 * NSEG + seg], 1);
    if (((y | x) & 7) == 0) atomicAdd(&cbins[3 * NSEG + seg], 1);
    __syncthreads();
    if (t < 4 * NSEG) {
        int c = cbins[t];
        if (c) atomicAdd(&counts[t], c);
    }
}

// Per-scale squared-diff channel-sum with compile-time constants so the
// channel loop unrolls with batched independent loads (8 dwordx4 in flight).
template <int S>
__device__ __forceinline__ void sq_accum(const float* __restrict__ F,
                                         const float* __restrict__ O,
                                         const unsigned char* __restrict__ seg0,
                                         float* __restrict__ bins,
                                         int tid)
{
    constexpr int C    = 256 << S;          // channels
    constexpr int lqpi = 12 - 2 * S;        // log2 float4s per (b,c) plane
    constexpr int hw4  = 1 << lqpi;
    constexpr int lw4  = 5 - S;             // log2 (w/4)
    constexpr int CH   = (S == 0) ? 32 : (S == 1) ? 16 : 8;  // channels/thread
    constexpr int lq   = 15 - 2 * S;        // log2 total quads (8 images)

    int qid = tid & ((1 << lq) - 1);        // pixel-quad id
    int c0  = (tid >> lq) * CH;             // first channel of this chunk
    int b   = qid >> lqpi;
    int within = qid & (hw4 - 1);

    size_t base4 = (size_t)(b * C + c0) * hw4 + within;
    const float4* pF = reinterpret_cast<const float4*>(F) + base4;
    const float4* pO = reinterpret_cast<const float4*>(O) + base4;

    float a0 = 0.f, a1 = 0.f, a2 = 0.f, a3 = 0.f;
    for (int i = 0; i < CH; i += 4) {
        // 8 independent 16B loads issued before any use -> 128 B/lane in flight
        float4 A0 = pF[(size_t)(i + 0) * hw4];
        float4 A1 = pF[(size_t)(i + 1) * hw4];
        float4 A2 = pF[(size_t)(i + 2) * hw4];
        float4 A3 = pF[(size_t)(i + 3) * hw4];
        float4 B0 = pO[(size_t)(i + 0) * hw4];
        float4 B1 = pO[(size_t)(i + 1) * hw4];
        float4 B2 = pO[(size_t)(i + 2) * hw4];
        float4 B3 = pO[(size_t)(i + 3) * hw4];
        float d;
        d = A0.x - B0.x; a0 = fmaf(d, d, a0);
        d = A0.y - B0.y; a1 = fmaf(d, d, a1);
        d = A0.z - B0.z; a2 = fmaf(d, d, a2);
        d = A0.w - B0.w; a3 = fmaf(d, d, a3);
        d = A1.x - B1.x; a0 = fmaf(d, d, a0);
        d = A1.y - B1.y; a1 = fmaf(d, d, a1);
        d = A1.z - B1.z; a2 = fmaf(d, d, a2);
        d = A1.w - B1.w; a3 = fmaf(d, d, a3);
        d = A2.x - B2.x; a0 = fmaf(d, d, a0);
        d = A2.y - B2.y; a1 = fmaf(d, d, a1);
        d = A2.z - B2.z; a2 = fmaf(d, d, a2);
        d = A2.w - B2.w; a3 = fmaf(d, d, a3);
        d = A3.x - B3.x; a0 = fmaf(d, d, a0);
        d = A3.y - B3.y; a1 = fmaf(d, d, a1);
        d = A3.z - B3.z; a2 = fmaf(d, d, a2);
        d = A3.w - B3.w; a3 = fmaf(d, d, a3);
    }

    // segments of the 4 pixels (map to scale-0 grid: *2^S)
    int y  = within >> lw4;
    int xq = within & ((1 << lw4) - 1);
    int segBase = (b << 14) + ((y << S) << 7) + ((xq << 2) << S);
    int g0 = seg0[segBase];
    int g1 = seg0[segBase + (1 << S)];
    int g2 = seg0[segBase + (2 << S)];
    int g3 = seg0[segBase + (3 << S)];
    if (g0 == g1 && g2 == g3 && g0 == g2) {
        atomicAdd(&bins[g0], (a0 + a1) + (a2 + a3));
    } else {
        atomicAdd(&bins[g0], a0);
        atomicAdd(&bins[g1], a1);
        atomicAdd(&bins[g2], a2);
        atomicAdd(&bins[g3], a3);
    }
}

// Blocks: [0,1024) s0, [1024,2048) s1, [2048,3072) s2, [3072,3584) s3.
__global__ __launch_bounds__(256) void sq_sum_kernel(
    const float* __restrict__ f0, const float* __restrict__ o0,
    const float* __restrict__ f1, const float* __restrict__ o1,
    const float* __restrict__ f2, const float* __restrict__ o2,
    const float* __restrict__ f3, const float* __restrict__ o3,
    const unsigned char* __restrict__ seg0,
    float* __restrict__ sums)
{
    __shared__ float bins[NSEG];
    if (threadIdx.x < NSEG) bins[threadIdx.x] = 0.0f;
    __syncthreads();

    int blk = blockIdx.x;
    int s_idx;
    if (blk < 1024) {
        s_idx = 0; sq_accum<0>(f0, o0, seg0, bins, blk * 256 + (int)threadIdx.x);
    } else if (blk < 2048) {
        s_idx = 1; sq_accum<1>(f1, o1, seg0, bins, (blk - 1024) * 256 + (int)threadIdx.x);
    } else if (blk < 3072) {
        s_idx = 2; sq_accum<2>(f2, o2, seg0, bins, (blk - 2048) * 256 + (int)threadIdx.x);
    } else {
        s_idx = 3; sq_accum<3>(f3, o3, seg0, bins, (blk - 3072) * 256 + (int)threadIdx.x);
    }

    __syncthreads();
    if (threadIdx.x < NSEG) {
        float v = bins[threadIdx.x];
        if (v != 0.0f) atomicAdd(&sums[s_idx * NSEG + threadIdx.x], v);
    }
}

__global__ void finalize_kernel(const float* __restrict__ sums,
                                const int* __restrict__ counts,
                                const int* __restrict__ p_ncls,
                                const int* __restrict__ p_nold,
                                int OC,
                                float* __restrict__ out)
{
    if (threadIdx.x != 0 || blockIdx.x != 0) return;
    int nold = p_nold[0];
    if (nold < 1 || nold > 100) nold = OC - 1;       // sanity fallback
    int ncls = p_ncls[0];
    if (ncls <= nold || ncls > 1000) ncls = 21;      // sanity fallback
    float w0 = (float)nold / (float)ncls;

    float loss = 0.0f;
    for (int s = 0; s < 4; ++s) {
        float Cs = (float)(256 << s);
        float sw = (float)(s + 1);                   // SCALE_WEIGHTS 1,2,3,4
        float acc = 0.0f;
        for (int g = 0; g <= nold; ++g) {            // dump bucket weight 0
            float w = (g == 0) ? w0 : 1.0f;
            int cnt = counts[s * NSEG + g];
            if (cnt > 0) acc += w * sums[s * NSEG + g] / ((float)cnt * Cs);
        }
        loss += sw * acc;
    }
    out[0] = loss * 0.25f;
}

extern "C" void kernel_launch(void* const* d_in, const int* in_sizes, int n_in,
                              void* d_out, int out_size, void* d_ws, size_t ws_size,
                              hipStream_t stream) {
    // setup_inputs dict order:
    // labels, outputs_old, feat0, feat_old0, feat1, feat_old1,
    // feat2, feat_old2, feat3, feat_old3, num_class, num_old_class
    const int*   labels      = (const int*)d_in[0];
    const float* outputs_old = (const float*)d_in[1];
    const float* f0 = (const float*)d_in[2];
    const float* o0 = (const float*)d_in[3];
    const float* f1 = (const float*)d_in[4];
    const float* o1 = (const float*)d_in[5];
    const float* f2 = (const float*)d_in[6];
    const float* o2 = (const float*)d_in[7];
    const float* f3 = (const float*)d_in[8];
    const float* o3 = (const float*)d_in[9];
    const int* p_ncls = (const int*)d_in[10];
    const int* p_nold = (const int*)d_in[11];

    int OC = in_sizes[1] / in_sizes[0];   // outputs_old channels = num_old_class + 1

    float* sums   = (float*)d_ws;
    int*   counts = (int*)((char*)d_ws + 4 * NSEG * sizeof(float));
    unsigned char* seg0 = (unsigned char*)d_ws + 1024;

    hipLaunchKernelGGL(init_accum, dim3(1), dim3(256), 0, stream, sums, counts);
    hipLaunchKernelGGL(seg_count_kernel, dim3(512), dim3(256), 0, stream,
                       labels, outputs_old, seg0, counts, OC);
    hipLaunchKernelGGL(sq_sum_kernel, dim3(3584), dim3(256), 0, stream,
                       f0, o0, f1, o1, f2, o2, f3, o3, seg0, sums);
    hipLaunchKernelGGL(finalize_kernel, dim3(1), dim3(64), 0, stream,
                       sums, counts, p_ncls, p_nold, OC, (float*)d_out);
}

// Round 7
// 119.271 us; speedup vs baseline: 1.2549x; 1.1602x over previous
//
#include <hip/hip_runtime.h>

#define NSEG 17

// ---------------- ws layout ----------------
// [0,    272)            : int   counts[4][17]
// [512,  784)            : float coef[4][17]
// [1024,   1024+131072)  : uint8 seg0b[8*128*128]
// [132096, +32768)       : uint8 seg1b[8*64*64]
// [164864, +8192)        : uint8 seg2b[8*32*32]
// [173056, +2048)        : uint8 seg3b[8*16*16]

__global__ void init_accum(int* __restrict__ counts) {
    int t = threadIdx.x;
    if (t < 4 * NSEG) counts[t] = 0;
}

// One thread per scale-0 pixel: per-scale seg byte maps + per-scale counts.
__global__ __launch_bounds__(256) void seg_count_kernel(
    const int* __restrict__ labels,         // [8,512,512]
    const float* __restrict__ outputs_old,  // [8,OC,512,512]
    unsigned char* __restrict__ seg0b,
    unsigned char* __restrict__ seg1b,
    unsigned char* __restrict__ seg2b,
    unsigned char* __restrict__ seg3b,
    int* __restrict__ counts,               // [4][17]
    int OC)
{
    __shared__ int cbins[4 * NSEG];
    int t = threadIdx.x;
    if (t < 4 * NSEG) cbins[t] = 0;
    __syncthreads();

    int p = blockIdx.x * 256 + t;           // [0, 131072)
    int b = p >> 14;
    int y = (p >> 7) & 127;
    int x = p & 127;
    int y0 = y << 2, x0 = x << 2;           // sampled position in 512 grid

    int lbl = labels[(b << 18) + (y0 << 9) + x0];

    // thresholded argmax, first-index-of-max (jnp.argmax semantics)
    const float* base = outputs_old + (((size_t)b * OC) << 18) + (y0 << 9) + x0;
    float best; int bidx = 0;
    if (OC == 16) {                          // fast path: 16 independent loads in flight
        float v[16];
        #pragma unroll
        for (int c = 0; c < 16; ++c) v[c] = base[(size_t)c << 18];
        #pragma unroll
        for (int c = 0; c < 16; ++c) v[c] = (v[c] < 0.5f) ? 0.0f : v[c];
        best = v[0];
        #pragma unroll
        for (int c = 1; c < 16; ++c) if (v[c] > best) { best = v[c]; bidx = c; }
    } else {
        float v0 = base[0];
        best = (v0 < 0.5f) ? 0.0f : v0;
        #pragma unroll 4
        for (int c = 1; c < OC; ++c) {
            float v = base[(size_t)c << 18];
            v = (v < 0.5f) ? 0.0f : v;
            if (v > best) { best = v; bidx = c; }
        }
    }

    int nold = OC - 1;
    int pl = (lbl == 0) ? bidx : lbl;
    int seg = (pl <= nold) ? pl : (nold + 1);

    seg0b[p] = (unsigned char)seg;
    atomicAdd(&cbins[seg], 1);
    if (((y | x) & 1) == 0) {
        seg1b[(b << 12) + ((y >> 1) << 6) + (x >> 1)] = (unsigned char)seg;
        atomicAdd(&cbins[NSEG + seg], 1);
    }
    if (((y | x) & 3) == 0) {
        seg2b[(b << 10) + ((y >> 2) << 5) + (x >> 2)] = (unsigned char)seg;
        atomicAdd(&cbins[2 * NSEG + seg], 1);
    }
    if (((y | x) & 7) == 0) {
        seg3b[(b << 8) + ((y >> 3) << 4) + (x >> 3)] = (unsigned char)seg;
        atomicAdd(&cbins[3 * NSEG + seg], 1);
    }
    __syncthreads();
    if (t < 4 * NSEG) {
        int c = cbins[t];
        if (c) atomicAdd(&counts[t], c);
    }
}

// coef[s][g] = 0.25 * (s+1) * cls_w[g] / (counts[s][g] * C_s); also zeroes out[0].
__global__ void coef_kernel(const int* __restrict__ counts,
                            const int* __restrict__ p_ncls,
                            const int* __restrict__ p_nold,
                            int OC,
                            float* __restrict__ coef,
                            float* __restrict__ out)
{
    int t = threadIdx.x;
    if (t == 0) out[0] = 0.0f;
    if (t >= 4 * NSEG) return;
    int s = t / NSEG, g = t % NSEG;
    int nold = p_nold[0];
    if (nold < 1 || nold > 100) nold = OC - 1;       // sanity fallback
    int ncls = p_ncls[0];
    if (ncls <= nold || ncls > 1000) ncls = 21;      // sanity fallback
    float w = (g == 0) ? (float)nold / (float)ncls : ((g <= nold) ? 1.0f : 0.0f);
    int cnt = counts[t];
    float c = 0.0f;
    if (cnt > 0 && w > 0.0f)
        c = 0.25f * (float)(s + 1) * w / ((float)cnt * (float)(256 << s));
    coef[t] = c;
}

// Linear-streaming weighted SSE. Each block owns 4096 contiguous float4-quads
// (128 KB of F + 128 KB of O, sequential HBM pattern). Per-pixel coefficient
// from a 17-entry LDS table (consecutive words -> 17 distinct banks,
// duplicate reads broadcast -> conflict-free). One atomic per block.
template <int S>
__device__ __forceinline__ float sq_stream(const float* __restrict__ F,
                                           const float* __restrict__ O,
                                           const unsigned* __restrict__ segq,
                                           const float* __restrict__ cf,  // LDS[17]
                                           int blk)
{
    constexpr int lqpi = 12 - 2 * S;        // log2 float4-quads per (b,c) plane
    constexpr int lgBC = lqpi + 8 + S;      // log2 quads per image (C * hw4)
    constexpr int hw4m = (1 << lqpi) - 1;

    const float4* pF = reinterpret_cast<const float4*>(F);
    const float4* pO = reinterpret_cast<const float4*>(O);
    int qbase = blk * 4096 + (int)threadIdx.x;

    float acc = 0.0f;
    #pragma unroll 2
    for (int k = 0; k < 16; k += 4) {
        int q0 = qbase + (k + 0) * 256;
        int q1 = qbase + (k + 1) * 256;
        int q2 = qbase + (k + 2) * 256;
        int q3 = qbase + (k + 3) * 256;
        unsigned g0 = segq[((q0 >> lgBC) << lqpi) | (q0 & hw4m)];
        unsigned g1 = segq[((q1 >> lgBC) << lqpi) | (q1 & hw4m)];
        unsigned g2 = segq[((q2 >> lgBC) << lqpi) | (q2 & hw4m)];
        unsigned g3 = segq[((q3 >> lgBC) << lqpi) | (q3 & hw4m)];
        float4 A0 = pF[q0], A1 = pF[q1], A2 = pF[q2], A3 = pF[q3];
        float4 B0 = pO[q0], B1 = pO[q1], B2 = pO[q2], B3 = pO[q3];
        float d, v;
        d = A0.x - B0.x; v  = cf[g0 & 255u]         * (d * d);
        d = A0.y - B0.y; v += cf[(g0 >> 8) & 255u]  * (d * d);
        d = A0.z - B0.z; v += cf[(g0 >> 16) & 255u] * (d * d);
        d = A0.w - B0.w; v += cf[g0 >> 24]          * (d * d);
        acc += v;
        d = A1.x - B1.x; v  = cf[g1 & 255u]         * (d * d);
        d = A1.y - B1.y; v += cf[(g1 >> 8) & 255u]  * (d * d);
        d = A1.z - B1.z; v += cf[(g1 >> 16) & 255u] * (d * d);
        d = A1.w - B1.w; v += cf[g1 >> 24]          * (d * d);
        acc += v;
        d = A2.x - B2.x; v  = cf[g2 & 255u]         * (d * d);
        d = A2.y - B2.y; v += cf[(g2 >> 8) & 255u]  * (d * d);
        d = A2.z - B2.z; v += cf[(g2 >> 16) & 255u] * (d * d);
        d = A2.w - B2.w; v += cf[g2 >> 24]          * (d * d);
        acc += v;
        d = A3.x - B3.x; v  = cf[g3 & 255u]         * (d * d);
        d = A3.y - B3.y; v += cf[(g3 >> 8) & 255u]  * (d * d);
        d = A3.z - B3.z; v += cf[(g3 >> 16) & 255u] * (d * d);
        d = A3.w - B3.w; v += cf[g3 >> 24]          * (d * d);
        acc += v;
    }
    return acc;
}

// Blocks: [0,2048) s0, [2048,3072) s1, [3072,3584) s2, [3584,3840) s3.
__global__ __launch_bounds__(256) void sq_sum_kernel(
    const float* __restrict__ f0, const float* __restrict__ o0,
    const float* __restrict__ f1, const float* __restrict__ o1,
    const float* __restrict__ f2, const float* __restrict__ o2,
    const float* __restrict__ f3, const float* __restrict__ o3,
    const unsigned* __restrict__ seg0q, const unsigned* __restrict__ seg1q,
    const unsigned* __restrict__ seg2q, const unsigned* __restrict__ seg3q,
    const float* __restrict__ coef,   // [4][17]
    float* __restrict__ out)
{
    __shared__ float cf[NSEG];
    __shared__ float wsum[4];

    int blk = blockIdx.x;
    int s_idx = (blk < 2048) ? 0 : (blk < 3072) ? 1 : (blk < 3584) ? 2 : 3;
    if (threadIdx.x < NSEG) cf[threadIdx.x] = coef[s_idx * NSEG + threadIdx.x];
    __syncthreads();

    float acc;
    if (s_idx == 0)      acc = sq_stream<0>(f0, o0, seg0q, cf, blk);
    else if (s_idx == 1) acc = sq_stream<1>(f1, o1, seg1q, cf, blk - 2048);
    else if (s_idx == 2) acc = sq_stream<2>(f2, o2, seg2q, cf, blk - 3072);
    else                 acc = sq_stream<3>(f3, o3, seg3q, cf, blk - 3584);

    #pragma unroll
    for (int off = 32; off > 0; off >>= 1) acc += __shfl_down(acc, off, 64);
    if ((threadIdx.x & 63) == 0) wsum[threadIdx.x >> 6] = acc;
    __syncthreads();
    if (threadIdx.x == 0)
        atomicAdd(out, (wsum[0] + wsum[1]) + (wsum[2] + wsum[3]));
}

extern "C" void kernel_launch(void* const* d_in, const int* in_sizes, int n_in,
                              void* d_out, int out_size, void* d_ws, size_t ws_size,
                              hipStream_t stream) {
    // setup_inputs dict order:
    // labels, outputs_old, feat0, feat_old0, feat1, feat_old1,
    // feat2, feat_old2, feat3, feat_old3, num_class, num_old_class
    const int*   labels      = (const int*)d_in[0];
    const float* outputs_old = (const float*)d_in[1];
    const float* f0 = (const float*)d_in[2];
    const float* o0 = (const float*)d_in[3];
    const float* f1 = (const float*)d_in[4];
    const float* o1 = (const float*)d_in[5];
    const float* f2 = (const float*)d_in[6];
    const float* o2 = (const float*)d_in[7];
    const float* f3 = (const float*)d_in[8];
    const float* o3 = (const float*)d_in[9];
    const int* p_ncls = (const int*)d_in[10];
    const int* p_nold = (const int*)d_in[11];

    int OC = in_sizes[1] / in_sizes[0];   // outputs_old channels = num_old_class + 1

    char* ws = (char*)d_ws;
    int*   counts = (int*)ws;                       // 272 B
    float* coef   = (float*)(ws + 512);             // 272 B
    unsigned char* seg0b = (unsigned char*)(ws + 1024);
    unsigned char* seg1b = (unsigned char*)(ws + 132096);
    unsigned char* seg2b = (unsigned char*)(ws + 164864);
    unsigned char* seg3b = (unsigned char*)(ws + 173056);

    hipLaunchKernelGGL(init_accum, dim3(1), dim3(128), 0, stream, counts);
    hipLaunchKernelGGL(seg_count_kernel, dim3(512), dim3(256), 0, stream,
                       labels, outputs_old, seg0b, seg1b, seg2b, seg3b, counts, OC);
    hipLaunchKernelGGL(coef_kernel, dim3(1), dim3(128), 0, stream,
                       counts, p_ncls, p_nold, OC, coef, (float*)d_out);
    hipLaunchKernelGGL(sq_sum_kernel, dim3(3840), dim3(256), 0, stream,
                       f0, o0, f1, o1, f2, o2, f3, o3,
                       (const unsigned*)seg0b, (const unsigned*)seg1b,
                       (const unsigned*)seg2b, (const unsigned*)seg3b,
                       coef, (float*)d_out);
}